// Round 2
// baseline (126.046 us; speedup 1.0000x reference)
//
#include <hip/hip_runtime.h>
#include <math.h>

// Problem: B=2, C=4, D=H=W=128. ROWS = B*C = 8 independent top-k rows.
#define ROWS 8
#define TPB  256
#define BINS 2048         // pass-1 bins: u >> 19 (v <= 1.0 -> bin <= 2032)
#define SHIFT1 19
#define BPR  256          // blocks per row for full-scan passes (2048 blocks total)

// ---------------- new-path state ----------------
struct State {
    unsigned int bsel[ROWS];      // selected pass-1 bin
    unsigned int krem[ROWS];      // remaining rank
    unsigned int tau[ROWS];       // final exact threshold bits
    unsigned int cand_cnt[ROWS];  // candidates appended
    double sum_hi[ROWS];          // sum of v strictly above candidate bin
    double sum_cand[ROWS];        // sum of candidates > tau
};

__device__ __forceinline__ float sq_err(float x, float t) {
    float s = 1.0f / (1.0f + __expf(-x));
    float d = s - t;
    return d * d;
}

// inclusive-suffix-scan rank select over TPB*PB bins; writes crossing bin and
// residual rank to shared outputs. All threads must call (internal barriers).
template<int PB>
__device__ void suffix_select(const unsigned int* h, unsigned int k,
                              unsigned int* ssum,
                              unsigned int* out_bin, unsigned int* out_krem) {
    const int t = threadIdx.x;
    unsigned int local[PB];
    unsigned int ts = 0;
#pragma unroll
    for (int j = 0; j < PB; ++j) { local[j] = h[t * PB + j]; ts += local[j]; }
    ssum[t] = ts;
    __syncthreads();
    for (int off = 1; off < TPB; off <<= 1) {
        unsigned int v = (t + off < TPB) ? ssum[t + off] : 0u;
        __syncthreads();
        ssum[t] += v;
        __syncthreads();
    }
    unsigned int above = ssum[t] - ts;   // count strictly above this thread's range
#pragma unroll
    for (int j = PB - 1; j >= 0; --j) {
        unsigned int c = local[j];
        if (above < k && above + c >= k) {   // exactly one (t,j) crosses
            *out_bin  = (unsigned int)(t * PB + j);
            *out_krem = k - above;
        }
        above += c;
    }
    __syncthreads();
}

__global__ void k_initN(unsigned int* __restrict__ hist, State* st) {
    const int base = blockIdx.x * 1024;
    for (int i = threadIdx.x; i < 1024; i += TPB) hist[base + i] = 0u;
    if (blockIdx.x == 0 && threadIdx.x < ROWS) {
        int r = threadIdx.x;
        st->bsel[r] = 0u; st->tau[r] = 0u; st->cand_cnt[r] = 0u;
        st->sum_hi[r] = 0.0; st->sum_cand[r] = 0.0;
        // krem set by host-side constant via k_setk below (avoid extra param here)
    }
}

__global__ void k_setk(State* st, unsigned int n) {
    if (threadIdx.x < ROWS) st->krem[threadIdx.x] = n;
}

// Pass 1: 2048-bin histogram of u>>19 per row.
__global__ __launch_bounds__(TPB) void k_hist1(const float4* __restrict__ x4,
                                               const float4* __restrict__ t4,
                                               unsigned int* __restrict__ hist,
                                               int N) {
    __shared__ unsigned int lh[BINS];
    const int row   = blockIdx.x / BPR;
    const int chunk = blockIdx.x % BPR;
    for (int i = threadIdx.x; i < BINS; i += TPB) lh[i] = 0u;
    __syncthreads();
    const int q4 = N / (BPR * 4);
    const long long base4 = (long long)row * (N / 4) + (long long)chunk * q4;
    for (int i = threadIdx.x; i < q4; i += TPB) {
        float4 xv = x4[base4 + i];
        float4 tv = t4[base4 + i];
        const float* xp = &xv.x;
        const float* tp = &tv.x;
#pragma unroll
        for (int j = 0; j < 4; ++j) {
            unsigned int u = __float_as_uint(sq_err(xp[j], tp[j]));
            atomicAdd(&lh[u >> SHIFT1], 1u);
        }
    }
    __syncthreads();
    for (int i = threadIdx.x; i < BINS; i += TPB) {
        unsigned int c = lh[i];
        if (c) atomicAdd(&hist[row * BINS + i], c);
    }
}

__global__ __launch_bounds__(TPB) void k_sel1(const unsigned int* __restrict__ hist,
                                              State* st) {
    __shared__ unsigned int ssum[TPB];
    __shared__ unsigned int sb, sk;
    const int row = blockIdx.x;
    unsigned int k = st->krem[row];
    suffix_select<8>(hist + row * BINS, k, ssum, &sb, &sk);
    if (threadIdx.x == 0) { st->bsel[row] = sb; st->krem[row] = sk; }
}

// Pass 2: sum v strictly above candidate bin; compact in-bin candidates.
__global__ __launch_bounds__(TPB) void k_pass2(const float4* __restrict__ x4,
                                               const float4* __restrict__ t4,
                                               State* st,
                                               unsigned int* __restrict__ cand,
                                               int N, unsigned int CAP) {
    __shared__ unsigned int sbuf[2048];
    __shared__ unsigned int scnt, sbase;
    __shared__ float sred[TPB];
    const int row   = blockIdx.x / BPR;
    const int chunk = blockIdx.x % BPR;
    if (threadIdx.x == 0) scnt = 0u;
    __syncthreads();
    const unsigned int bsel = st->bsel[row];
    const int q4 = N / (BPR * 4);
    const long long base4 = (long long)row * (N / 4) + (long long)chunk * q4;
    float acc = 0.0f;
    for (int i = threadIdx.x; i < q4; i += TPB) {
        float4 xv = x4[base4 + i];
        float4 tv = t4[base4 + i];
        const float* xp = &xv.x;
        const float* tp = &tv.x;
#pragma unroll
        for (int j = 0; j < 4; ++j) {
            float v = sq_err(xp[j], tp[j]);
            unsigned int u = __float_as_uint(v);
            unsigned int b = u >> SHIFT1;
            if (b > bsel) {
                acc += v;
            } else if (b == bsel) {
                unsigned int p = atomicAdd(&scnt, 1u);
                if (p < 2048u) sbuf[p] = u;
                else {                          // rare LDS-stage overflow: spill direct
                    unsigned int g = atomicAdd(&st->cand_cnt[row], 1u);
                    if (g < CAP) cand[(size_t)row * CAP + g] = u;
                }
            }
        }
    }
    sred[threadIdx.x] = acc;
    __syncthreads();
    for (int off = TPB / 2; off > 0; off >>= 1) {
        if (threadIdx.x < off) sred[threadIdx.x] += sred[threadIdx.x + off];
        __syncthreads();
    }
    if (threadIdx.x == 0) {
        if (sred[0] != 0.0f) atomicAdd(&st->sum_hi[row], (double)sred[0]);
        sbase = atomicAdd(&st->cand_cnt[row], min(scnt, 2048u));
    }
    __syncthreads();
    unsigned int cnt = min(scnt, 2048u);
    for (unsigned int i = threadIdx.x; i < cnt; i += TPB) {
        unsigned int g = sbase + i;
        if (g < CAP) cand[(size_t)row * CAP + g] = sbuf[i];
    }
}

// Per-row candidate selection (remaining 19 bits) + tie handling + sum > tau.
__global__ __launch_bounds__(TPB) void k_candsel(State* st,
                                                 const unsigned int* __restrict__ cand,
                                                 unsigned int CAP) {
    __shared__ unsigned int lh[1024];
    __shared__ unsigned int ssum[TPB];
    __shared__ unsigned int sb, sk;
    __shared__ float sred[TPB];
    const int row = blockIdx.x;
    const unsigned int cnt = min(st->cand_cnt[row], CAP);
    unsigned int k = st->krem[row];
    const unsigned int* cp = cand + (size_t)row * CAP;

    // phase A: bits [18:9] (1024 bins)
    for (int i = threadIdx.x; i < 1024; i += TPB) lh[i] = 0u;
    __syncthreads();
    for (unsigned int i = threadIdx.x; i < cnt; i += TPB)
        atomicAdd(&lh[(cp[i] >> 9) & 1023u], 1u);
    __syncthreads();
    suffix_select<4>(lh, k, ssum, &sb, &sk);
    unsigned int b2 = sb;
    k = sk;
    __syncthreads();

    // phase B: bits [8:0] (512 bins) among bin-b2 candidates
    for (int i = threadIdx.x; i < 512; i += TPB) lh[i] = 0u;
    __syncthreads();
    for (unsigned int i = threadIdx.x; i < cnt; i += TPB) {
        unsigned int u = cp[i];
        if (((u >> 9) & 1023u) == b2) atomicAdd(&lh[u & 511u], 1u);
    }
    __syncthreads();
    suffix_select<2>(lh, k, ssum, &sb, &sk);
    unsigned int tau   = (st->bsel[row] << SHIFT1) | (b2 << 9) | sb;
    unsigned int krem3 = sk;
    __syncthreads();

    // phase C: sum candidates strictly > tau
    float acc = 0.0f;
    for (unsigned int i = threadIdx.x; i < cnt; i += TPB) {
        unsigned int u = cp[i];
        if (u > tau) acc += __uint_as_float(u);
    }
    sred[threadIdx.x] = acc;
    __syncthreads();
    for (int off = TPB / 2; off > 0; off >>= 1) {
        if (threadIdx.x < off) sred[threadIdx.x] += sred[threadIdx.x + off];
        __syncthreads();
    }
    if (threadIdx.x == 0) {
        st->tau[row] = tau;
        st->krem[row] = krem3;
        st->sum_cand[row] = (double)sred[0];
    }
}

__global__ void k_finalN(const State* __restrict__ st, float* __restrict__ out,
                         unsigned int n) {
    if (threadIdx.x == 0 && blockIdx.x == 0) {
        double tot = 0.0;
        for (int r = 0; r < ROWS; ++r) {
            tot += st->sum_hi[r] + st->sum_cand[r]
                 + (double)st->krem[r] * (double)__uint_as_float(st->tau[r]);
        }
        out[0] = (float)(tot / ((double)ROWS * (double)n));
    }
}

// ================= fallback path (R0, proven): 3 radix passes + sum =================
struct SelState {
    unsigned int prefix[ROWS];
    unsigned int krem[ROWS];
    unsigned int tau[ROWS];
    double       sum_gt[ROWS];
};

__global__ void k_init(unsigned int* __restrict__ hist, SelState* st, unsigned int n) {
    int t = threadIdx.x;
    for (int i = t; i < ROWS * BINS; i += TPB) hist[i] = 0;
    if (t < ROWS) {
        st->prefix[t] = 0u; st->krem[t] = n; st->tau[t] = 0u; st->sum_gt[t] = 0.0;
    }
}

__global__ __launch_bounds__(TPB) void k_hist(const float4* __restrict__ x4,
                                              const float4* __restrict__ t4,
                                              unsigned int* __restrict__ hist,
                                              const SelState* __restrict__ st,
                                              int N, unsigned int himask, int shift,
                                              unsigned int binmask) {
    __shared__ unsigned int lh[BINS];
    const int row   = blockIdx.x / 128;
    const int chunk = blockIdx.x % 128;
    for (int i = threadIdx.x; i < BINS; i += TPB) lh[i] = 0u;
    __syncthreads();
    const unsigned int pref = st->prefix[row];
    const int q4 = N / (128 * 4);
    const long long base4 = (long long)row * (N / 4) + (long long)chunk * q4;
    for (int i = threadIdx.x; i < q4; i += TPB) {
        float4 xv = x4[base4 + i];
        float4 tv = t4[base4 + i];
        const float* xp = &xv.x;
        const float* tp = &tv.x;
#pragma unroll
        for (int j = 0; j < 4; ++j) {
            unsigned int u = __float_as_uint(sq_err(xp[j], tp[j]));
            if ((u & himask) == pref) atomicAdd(&lh[(u >> shift) & binmask], 1u);
        }
    }
    __syncthreads();
    for (int i = threadIdx.x; i < BINS; i += TPB) {
        unsigned int c = lh[i];
        if (c) atomicAdd(&hist[row * BINS + i], c);
    }
}

__global__ __launch_bounds__(TPB) void k_select(unsigned int* __restrict__ hist,
                                                SelState* st, int shift, int bins, int last) {
    const int row = blockIdx.x;
    const int t   = threadIdx.x;
    const int pb  = bins / TPB;
    unsigned int* h = &hist[row * BINS];
    const unsigned int k    = st->krem[row];
    const unsigned int pref = st->prefix[row];
    unsigned int local[8];
    unsigned int ts = 0;
    for (int j = 0; j < pb; ++j) { local[j] = h[t * pb + j]; ts += local[j]; }
    __shared__ unsigned int ssum[TPB];
    ssum[t] = ts;
    __syncthreads();
    for (int off = 1; off < TPB; off <<= 1) {
        unsigned int val = (t + off < TPB) ? ssum[t + off] : 0u;
        __syncthreads();
        ssum[t] += val;
        __syncthreads();
    }
    unsigned int above = ssum[t] - ts;
    for (int j = pb - 1; j >= 0; --j) {
        unsigned int c = local[j];
        if (above < k && above + c >= k) {
            unsigned int b  = (unsigned int)(t * pb + j);
            st->krem[row]   = k - above;
            st->prefix[row] = pref | (b << shift);
            if (last) st->tau[row] = pref | (b << shift);
        }
        above += c;
    }
    for (int j = 0; j < pb; ++j) h[t * pb + j] = 0u;
}

__global__ __launch_bounds__(TPB) void k_sum(const float4* __restrict__ x4,
                                             const float4* __restrict__ t4,
                                             SelState* st, int N) {
    const int row   = blockIdx.x / 128;
    const int chunk = blockIdx.x % 128;
    const unsigned int tau = st->tau[row];
    const int q4 = N / (128 * 4);
    const long long base4 = (long long)row * (N / 4) + (long long)chunk * q4;
    double acc = 0.0;
    for (int i = threadIdx.x; i < q4; i += TPB) {
        float4 xv = x4[base4 + i];
        float4 tv = t4[base4 + i];
        const float* xp = &xv.x;
        const float* tp = &tv.x;
#pragma unroll
        for (int j = 0; j < 4; ++j) {
            float v = sq_err(xp[j], tp[j]);
            if (__float_as_uint(v) > tau) acc += (double)v;
        }
    }
    __shared__ double sh[TPB];
    sh[threadIdx.x] = acc;
    __syncthreads();
    for (int off = TPB / 2; off > 0; off >>= 1) {
        if (threadIdx.x < off) sh[threadIdx.x] += sh[threadIdx.x + off];
        __syncthreads();
    }
    if (threadIdx.x == 0) atomicAdd(&st->sum_gt[row], sh[0]);
}

__global__ void k_final(const SelState* __restrict__ st, float* __restrict__ out,
                        unsigned int n) {
    if (threadIdx.x == 0 && blockIdx.x == 0) {
        double tot = 0.0;
        for (int r = 0; r < ROWS; ++r)
            tot += st->sum_gt[r] + (double)st->krem[r] * (double)__uint_as_float(st->tau[r]);
        out[0] = (float)(tot / ((double)ROWS * (double)n));
    }
}

// =====================================================================

extern "C" void kernel_launch(void* const* d_in, const int* in_sizes, int n_in,
                              void* d_out, int out_size, void* d_ws, size_t ws_size,
                              hipStream_t stream) {
    const float* x  = (const float*)d_in[0];
    const float* tg = (const float*)d_in[1];
    float* out = (float*)d_out;

    const int total = in_sizes[0];
    const int N     = total / ROWS;                       // 2,097,152
    unsigned int n  = (unsigned int)llround((double)N * 0.10);
    if (n < 1) n = 1;

    const float4* x4 = (const float4*)x;
    const float4* t4 = (const float4*)tg;
    dim3 b(TPB);

    const size_t histBytes = (size_t)ROWS * BINS * sizeof(unsigned int);  // 64 KB
    const size_t statePad  = 512;
    const size_t candOff   = histBytes + statePad;

    size_t capElems = 0;
    if (ws_size > candOff) capElems = (ws_size - candOff) / (ROWS * sizeof(unsigned int));
    if (capElems > (size_t)N) capElems = (size_t)N;

    if (capElems >= 65536) {
        // ---------- fast path: 2 full passes + tiny candidate work ----------
        unsigned int CAP = (unsigned int)capElems;
        unsigned int* hist = (unsigned int*)d_ws;
        State* st = (State*)((char*)d_ws + histBytes);
        unsigned int* cand = (unsigned int*)((char*)d_ws + candOff);

        dim3 gBig(ROWS * BPR);
        k_initN<<<dim3(16), b, 0, stream>>>(hist, st);
        k_setk<<<dim3(1), dim3(64), 0, stream>>>(st, n);
        k_hist1<<<gBig, b, 0, stream>>>(x4, t4, hist, N);
        k_sel1<<<dim3(ROWS), b, 0, stream>>>(hist, st);
        k_pass2<<<gBig, b, 0, stream>>>(x4, t4, st, cand, N, CAP);
        k_candsel<<<dim3(ROWS), b, 0, stream>>>(st, cand, CAP);
        k_finalN<<<dim3(1), dim3(64), 0, stream>>>(st, out, n);
    } else {
        // ---------- fallback: proven 3-pass radix + sum ----------
        unsigned int* hist = (unsigned int*)d_ws;
        SelState* st = (SelState*)((char*)d_ws + histBytes);
        dim3 gBig(ROWS * 128);
        k_init<<<dim3(1), b, 0, stream>>>(hist, st, n);
        k_hist<<<gBig, b, 0, stream>>>(x4, t4, hist, st, N, 0x00000000u, 21, 2047u);
        k_select<<<dim3(ROWS), b, 0, stream>>>(hist, st, 21, 2048, 0);
        k_hist<<<gBig, b, 0, stream>>>(x4, t4, hist, st, N, 0xFFE00000u, 10, 2047u);
        k_select<<<dim3(ROWS), b, 0, stream>>>(hist, st, 10, 2048, 0);
        k_hist<<<gBig, b, 0, stream>>>(x4, t4, hist, st, N, 0xFFFFFC00u, 0, 1023u);
        k_select<<<dim3(ROWS), b, 0, stream>>>(hist, st, 0, 1024, 1);
        k_sum<<<gBig, b, 0, stream>>>(x4, t4, st, N);
        k_final<<<dim3(1), dim3(64), 0, stream>>>(st, out, n);
    }
}